// Round 5
// baseline (256.715 us; speedup 1.0000x reference)
//
#include <hip/hip_runtime.h>
#include <hip/hip_bf16.h>

#define D_IN  768
#define D_E   256
#define M_TOT 512      // B*S
#define E_TOT 100000

typedef __attribute__((ext_vector_type(4))) float f32x4;
typedef __attribute__((ext_vector_type(8))) short bf16x8;

__device__ __forceinline__ unsigned short bf16bits(float f) {
    union { __hip_bfloat16 h; unsigned short u; } c;
    c.h = __float2bfloat16(f);
    return c.u;
}

// ---------------------------------------------------------------------------
// Kernel 0: eb[n][k] = bf16( en[n][k] / ||en[n]|| )
// ---------------------------------------------------------------------------
__global__ __launch_bounds__(256) void prep_kernel(
    const float* __restrict__ en, unsigned short* __restrict__ eb)
{
    const int lane = threadIdx.x & 63;
    const int gw   = blockIdx.x * 4 + (threadIdx.x >> 6);
    #pragma unroll 2
    for (int i = 0; i < 8; ++i) {
        const int row = gw * 8 + i;
        const float4 v = *reinterpret_cast<const float4*>(
            en + (size_t)row * D_E + lane * 4);
        float s = v.x*v.x + v.y*v.y + v.z*v.z + v.w*v.w;
        #pragma unroll
        for (int off = 1; off < 64; off <<= 1) s += __shfl_xor(s, off, 64);
        const float sc = 1.0f / fmaxf(sqrtf(s), 1e-8f);
        union { unsigned short u[4]; uint2 d; } o;
        o.u[0] = bf16bits(v.x * sc); o.u[1] = bf16bits(v.y * sc);
        o.u[2] = bf16bits(v.z * sc); o.u[3] = bf16bits(v.w * sc);
        *reinterpret_cast<uint2*>(eb + (size_t)row * D_E + lane * 4) = o.d;
    }
}

// ---------------------------------------------------------------------------
// Kernel 1: qb[m][e] = bf16( tanh(x@W^T + b) / ||row|| )
// ---------------------------------------------------------------------------
#define PTM 8
#define PBK 64
#define PROUNDS (D_IN / PBK)   // 12

__global__ __launch_bounds__(256) void proj_kernel(
    const float* __restrict__ x, const float* __restrict__ W,
    const float* __restrict__ b, unsigned short* __restrict__ qb)
{
    __shared__ float ws[D_E * (PBK + 1)];
    __shared__ float xs[PTM][PBK];
    __shared__ float red[PTM][4];

    const int t  = threadIdx.x;
    const int m0 = blockIdx.x * PTM;
    const int c4 = t & 15;
    const int rr = t >> 4;
    float4 wreg[16];
    float  xreg[2];
    float  acc[PTM];
    #pragma unroll
    for (int m = 0; m < PTM; ++m) acc[m] = 0.f;

    #pragma unroll
    for (int i = 0; i < 16; ++i)
        wreg[i] = *reinterpret_cast<const float4*>(
            &W[(size_t)(i * 16 + rr) * D_IN + c4 * 4]);
    #pragma unroll
    for (int i = 0; i < 2; ++i) {
        int f = i * 256 + t;
        xreg[i] = x[(size_t)(m0 + (f >> 6)) * D_IN + (f & 63)];
    }

    for (int rd = 0; rd < PROUNDS; ++rd) {
        #pragma unroll
        for (int i = 0; i < 16; ++i) {
            float* dst = &ws[(i * 16 + rr) * (PBK + 1) + c4 * 4];
            dst[0] = wreg[i].x; dst[1] = wreg[i].y;
            dst[2] = wreg[i].z; dst[3] = wreg[i].w;
        }
        #pragma unroll
        for (int i = 0; i < 2; ++i) {
            int f = i * 256 + t;
            xs[f >> 6][f & 63] = xreg[i];
        }
        __syncthreads();
        if (rd + 1 < PROUNDS) {
            const int k0 = (rd + 1) * PBK;
            #pragma unroll
            for (int i = 0; i < 16; ++i)
                wreg[i] = *reinterpret_cast<const float4*>(
                    &W[(size_t)(i * 16 + rr) * D_IN + k0 + c4 * 4]);
            #pragma unroll
            for (int i = 0; i < 2; ++i) {
                int f = i * 256 + t;
                xreg[i] = x[(size_t)(m0 + (f >> 6)) * D_IN + k0 + (f & 63)];
            }
        }
        #pragma unroll
        for (int k = 0; k < PBK; ++k) {
            float wv = ws[t * (PBK + 1) + k];
            #pragma unroll
            for (int m = 0; m < PTM; ++m)
                acc[m] = fmaf(xs[m][k], wv, acc[m]);
        }
        __syncthreads();
    }

    const int lane = t & 63, wid = t >> 6;
    const float bias = b[t];
    float q[PTM];
    #pragma unroll
    for (int m = 0; m < PTM; ++m) {
        q[m] = tanhf(acc[m] + bias);
        float s = q[m] * q[m];
        #pragma unroll
        for (int off = 1; off < 64; off <<= 1) s += __shfl_xor(s, off, 64);
        if (lane == 0) red[m][wid] = s;
    }
    __syncthreads();
    #pragma unroll
    for (int m = 0; m < PTM; ++m) {
        float s = red[m][0] + red[m][1] + red[m][2] + red[m][3];
        float qinv = 1.0f / fmaxf(sqrtf(s), 1e-8f);
        qb[(size_t)(m0 + m) * D_E + t] = bf16bits(q[m] * qinv);
    }
}

// ---------------------------------------------------------------------------
// Kernel 2: out[m][n] = qn[m] . en_hat[n]  (both pre-normalized bf16)
// WRITE-LOCALITY EXPERIMENT: block = 32m x 512n (8 waves side-by-side in n,
// wave = 32m x 64n) -> each output row gets 2 KB contiguous from one block,
// written near-simultaneously (page-friendly), vs 256 B in all prior rounds.
// No LDS, no barriers: q panel persistent in regs (16 frags, loaded once,
// shared m-rows across waves -> L1/L2 hot); entities streamed bf16 direct
// from L2/L3 (prep output). Fully-unrolled 32-load / 64-MFMA body.
// ---------------------------------------------------------------------------
#define BMB 32
#define BNB 512
#define NGN ((E_TOT + BNB - 1) / BNB)   // 196
#define NGM (M_TOT / BMB)               // 16
#define SIM_GRID (NGN * NGM)            // 3136 (%8 == 0)

__global__ __launch_bounds__(512, 2) void sim_kernel(
    const unsigned short* __restrict__ eb, const unsigned short* __restrict__ qb,
    float* __restrict__ out)
{
    const int t    = threadIdx.x;
    const int lane = t & 63;
    const int wid  = t >> 6;        // 0..7: n sub-panel within block
    const int l15  = lane & 15;
    const int lk   = lane >> 4;     // 0..3: k-chunk / n-subrow group

    // chunked bijective XCD swizzle: the 16 m-blocks of one n-group are
    // virtually consecutive -> same XCD -> entity slice L2 reuse.
    const int vbid = (blockIdx.x & 7) * (SIM_GRID / 8) + (blockIdx.x >> 3);
    const int ng = vbid >> 4;       // 0..195
    const int mg = vbid & 15;       // 0..15
    const int m0 = mg * BMB;
    const int n0 = ng * BNB + wid * 64;

    // ---- persistent q panel: 2 m-frags x 8 ks = 64 VGPR, loaded once ----
    bf16x8 qf[2][8];
    #pragma unroll
    for (int mf = 0; mf < 2; ++mf) {
        const unsigned short* base =
            qb + (size_t)(m0 + mf * 16 + l15) * D_E + lk * 8;
        #pragma unroll
        for (int ks = 0; ks < 8; ++ks)
            qf[mf][ks] = *reinterpret_cast<const bf16x8*>(base + ks * 32);
    }

    const unsigned short* erow[4];
    #pragma unroll
    for (int nf = 0; nf < 4; ++nf) {
        int n = n0 + nf * 16 + l15;
        if (n >= E_TOT) n = E_TOT - 1;   // clamp loads; stores masked below
        erow[nf] = eb + (size_t)n * D_E + lk * 8;
    }

    f32x4 acc[2][4];
    #pragma unroll
    for (int mf = 0; mf < 2; ++mf)
        #pragma unroll
        for (int nf = 0; nf < 4; ++nf)
            acc[mf][nf] = (f32x4){0.f, 0.f, 0.f, 0.f};

    #pragma unroll
    for (int ks = 0; ks < 8; ++ks) {
        bf16x8 ef[4];
        #pragma unroll
        for (int nf = 0; nf < 4; ++nf)
            ef[nf] = *reinterpret_cast<const bf16x8*>(erow[nf] + ks * 32);
        #pragma unroll
        for (int mf = 0; mf < 2; ++mf)
            #pragma unroll
            for (int nf = 0; nf < 4; ++nf)
                acc[mf][nf] = __builtin_amdgcn_mfma_f32_16x16x32_bf16(
                    ef[nf], qf[mf][ks], acc[mf][nf], 0, 0, 0);
    }

    #pragma unroll
    for (int mf = 0; mf < 2; ++mf) {
        const int m = m0 + mf * 16 + l15;
        #pragma unroll
        for (int nf = 0; nf < 4; ++nf) {
            const int n = n0 + nf * 16 + lk * 4;
            if (n < E_TOT)                 // E%4==0 -> whole f32x4 valid
                *reinterpret_cast<f32x4*>(&out[(size_t)m * E_TOT + n]) =
                    acc[mf][nf];
        }
    }
}

// ---------------------------------------------------------------------------
extern "C" void kernel_launch(void* const* d_in, const int* in_sizes, int n_in,
                              void* d_out, int out_size, void* d_ws, size_t ws_size,
                              hipStream_t stream) {
    const float* x  = (const float*)d_in[0];   // [4,128,768]
    const float* W  = (const float*)d_in[1];   // [256,768]
    const float* b  = (const float*)d_in[2];   // [256]
    const float* en = (const float*)d_in[3];   // [100000,256]
    float* out = (float*)d_out;                // [512,100000]

    unsigned short* qb = (unsigned short*)d_ws;                 // 256 KB
    unsigned short* eb = (unsigned short*)((char*)d_ws + (size_t)M_TOT * D_E * 2);

    prep_kernel<<<E_TOT / 32, 256, 0, stream>>>(en, eb);        // 3125 blocks
    proj_kernel<<<M_TOT / PTM, 256, 0, stream>>>(x, W, b, qb);  // 64 blocks
    sim_kernel<<<SIM_GRID, 512, 0, stream>>>(eb, qb, out);      // 3136 blocks
}

// Round 6
// 254.879 us; speedup vs baseline: 1.0072x; 1.0072x over previous
//
#include <hip/hip_runtime.h>
#include <hip/hip_bf16.h>

#define D_IN  768
#define D_E   256
#define M_TOT 512      // B*S
#define E_TOT 100000

typedef __attribute__((ext_vector_type(4))) float f32x4;
typedef __attribute__((ext_vector_type(8))) short bf16x8;

__device__ __forceinline__ unsigned short bf16bits(float f) {
    union { __hip_bfloat16 h; unsigned short u; } c;
    c.h = __float2bfloat16(f);
    return c.u;
}

// ---------------------------------------------------------------------------
// Kernel 0: eb[n][k] = bf16( en[n][k] / ||en[n]|| )
// ---------------------------------------------------------------------------
__global__ __launch_bounds__(256) void prep_kernel(
    const float* __restrict__ en, unsigned short* __restrict__ eb)
{
    const int lane = threadIdx.x & 63;
    const int gw   = blockIdx.x * 4 + (threadIdx.x >> 6);
    #pragma unroll 2
    for (int i = 0; i < 8; ++i) {
        const int row = gw * 8 + i;
        const float4 v = *reinterpret_cast<const float4*>(
            en + (size_t)row * D_E + lane * 4);
        float s = v.x*v.x + v.y*v.y + v.z*v.z + v.w*v.w;
        #pragma unroll
        for (int off = 1; off < 64; off <<= 1) s += __shfl_xor(s, off, 64);
        const float sc = 1.0f / fmaxf(sqrtf(s), 1e-8f);
        union { unsigned short u[4]; uint2 d; } o;
        o.u[0] = bf16bits(v.x * sc); o.u[1] = bf16bits(v.y * sc);
        o.u[2] = bf16bits(v.z * sc); o.u[3] = bf16bits(v.w * sc);
        *reinterpret_cast<uint2*>(eb + (size_t)row * D_E + lane * 4) = o.d;
    }
}

// ---------------------------------------------------------------------------
// Kernel 1: qb[m][e] = bf16( tanh(x@W^T + b) / ||row|| )
// ---------------------------------------------------------------------------
#define PTM 8
#define PBK 64
#define PROUNDS (D_IN / PBK)   // 12

__global__ __launch_bounds__(256) void proj_kernel(
    const float* __restrict__ x, const float* __restrict__ W,
    const float* __restrict__ b, unsigned short* __restrict__ qb)
{
    __shared__ float ws[D_E * (PBK + 1)];
    __shared__ float xs[PTM][PBK];
    __shared__ float red[PTM][4];

    const int t  = threadIdx.x;
    const int m0 = blockIdx.x * PTM;
    const int c4 = t & 15;
    const int rr = t >> 4;
    float4 wreg[16];
    float  xreg[2];
    float  acc[PTM];
    #pragma unroll
    for (int m = 0; m < PTM; ++m) acc[m] = 0.f;

    #pragma unroll
    for (int i = 0; i < 16; ++i)
        wreg[i] = *reinterpret_cast<const float4*>(
            &W[(size_t)(i * 16 + rr) * D_IN + c4 * 4]);
    #pragma unroll
    for (int i = 0; i < 2; ++i) {
        int f = i * 256 + t;
        xreg[i] = x[(size_t)(m0 + (f >> 6)) * D_IN + (f & 63)];
    }

    for (int rd = 0; rd < PROUNDS; ++rd) {
        #pragma unroll
        for (int i = 0; i < 16; ++i) {
            float* dst = &ws[(i * 16 + rr) * (PBK + 1) + c4 * 4];
            dst[0] = wreg[i].x; dst[1] = wreg[i].y;
            dst[2] = wreg[i].z; dst[3] = wreg[i].w;
        }
        #pragma unroll
        for (int i = 0; i < 2; ++i) {
            int f = i * 256 + t;
            xs[f >> 6][f & 63] = xreg[i];
        }
        __syncthreads();
        if (rd + 1 < PROUNDS) {
            const int k0 = (rd + 1) * PBK;
            #pragma unroll
            for (int i = 0; i < 16; ++i)
                wreg[i] = *reinterpret_cast<const float4*>(
                    &W[(size_t)(i * 16 + rr) * D_IN + k0 + c4 * 4]);
            #pragma unroll
            for (int i = 0; i < 2; ++i) {
                int f = i * 256 + t;
                xreg[i] = x[(size_t)(m0 + (f >> 6)) * D_IN + k0 + (f & 63)];
            }
        }
        #pragma unroll
        for (int k = 0; k < PBK; ++k) {
            float wv = ws[t * (PBK + 1) + k];
            #pragma unroll
            for (int m = 0; m < PTM; ++m)
                acc[m] = fmaf(xs[m][k], wv, acc[m]);
        }
        __syncthreads();
    }

    const int lane = t & 63, wid = t >> 6;
    const float bias = b[t];
    float q[PTM];
    #pragma unroll
    for (int m = 0; m < PTM; ++m) {
        q[m] = tanhf(acc[m] + bias);
        float s = q[m] * q[m];
        #pragma unroll
        for (int off = 1; off < 64; off <<= 1) s += __shfl_xor(s, off, 64);
        if (lane == 0) red[m][wid] = s;
    }
    __syncthreads();
    #pragma unroll
    for (int m = 0; m < PTM; ++m) {
        float s = red[m][0] + red[m][1] + red[m][2] + red[m][3];
        float qinv = 1.0f / fmaxf(sqrtf(s), 1e-8f);
        qb[(size_t)(m0 + m) * D_E + t] = bf16bits(q[m] * qinv);
    }
}

// ---------------------------------------------------------------------------
// Kernel 2: out[m][n] = qn[m] . en_hat[n]  (both pre-normalized bf16)
// IDENTICAL compute to round 5 (persistent q regs, direct bf16 entity loads,
// 32m x 512n block of 8 waves). ONE CHANGE: LDS-transposed epilogue.
// acc -> LDS tile [32][516] f32 (66 KB), barrier, then each wave-store writes
// 1 KB CONTIGUOUS of a single output row (rows leave in order, 2 KB/row
// back-to-back) instead of 16 rows x 64B scatter. Tests the hypothesis that
// DRAM write locality (not bytes) is the 1.5 TB/s limiter.
// ---------------------------------------------------------------------------
#define BMB 32
#define BNB 512
#define NGN ((E_TOT + BNB - 1) / BNB)   // 196
#define NGM (M_TOT / BMB)               // 16
#define SIM_GRID (NGN * NGM)            // 3136 (%8 == 0)

#define OTP 516   // row pad: 516%32=4 -> 2-way LDS banks (free)

__global__ __launch_bounds__(512, 2) void sim_kernel(
    const unsigned short* __restrict__ eb, const unsigned short* __restrict__ qb,
    float* __restrict__ out)
{
    __shared__ float ot[BMB][OTP];   // 66 KB

    const int t    = threadIdx.x;
    const int lane = t & 63;
    const int wid  = t >> 6;        // 0..7: n sub-panel within block
    const int l15  = lane & 15;
    const int lk   = lane >> 4;     // 0..3

    // chunked bijective XCD swizzle: the 16 m-blocks of one n-group are
    // virtually consecutive -> same XCD -> entity slice L2 reuse.
    const int vbid = (blockIdx.x & 7) * (SIM_GRID / 8) + (blockIdx.x >> 3);
    const int ng = vbid >> 4;       // 0..195
    const int mg = vbid & 15;       // 0..15
    const int m0 = mg * BMB;
    const int n0 = ng * BNB;
    const int nw = wid * 64;

    // ---- persistent q panel: 2 m-frags x 8 ks = 64 regs, loaded once ----
    bf16x8 qf[2][8];
    #pragma unroll
    for (int mf = 0; mf < 2; ++mf) {
        const unsigned short* base =
            qb + (size_t)(m0 + mf * 16 + l15) * D_E + lk * 8;
        #pragma unroll
        for (int ks = 0; ks < 8; ++ks)
            qf[mf][ks] = *reinterpret_cast<const bf16x8*>(base + ks * 32);
    }

    const unsigned short* erow[4];
    #pragma unroll
    for (int nf = 0; nf < 4; ++nf) {
        int n = n0 + nw + nf * 16 + l15;
        if (n >= E_TOT) n = E_TOT - 1;   // clamp loads; stores masked below
        erow[nf] = eb + (size_t)n * D_E + lk * 8;
    }

    f32x4 acc[2][4];
    #pragma unroll
    for (int mf = 0; mf < 2; ++mf)
        #pragma unroll
        for (int nf = 0; nf < 4; ++nf)
            acc[mf][nf] = (f32x4){0.f, 0.f, 0.f, 0.f};

    #pragma unroll
    for (int ks = 0; ks < 8; ++ks) {
        bf16x8 ef[4];
        #pragma unroll
        for (int nf = 0; nf < 4; ++nf)
            ef[nf] = *reinterpret_cast<const bf16x8*>(erow[nf] + ks * 32);
        #pragma unroll
        for (int mf = 0; mf < 2; ++mf)
            #pragma unroll
            for (int nf = 0; nf < 4; ++nf)
                acc[mf][nf] = __builtin_amdgcn_mfma_f32_16x16x32_bf16(
                    ef[nf], qf[mf][ks], acc[mf][nf], 0, 0, 0);
    }

    // ---- epilogue: acc -> LDS [m][n], then linear 1KB-contiguous stores ----
    #pragma unroll
    for (int mf = 0; mf < 2; ++mf) {
        const int m = mf * 16 + l15;
        #pragma unroll
        for (int nf = 0; nf < 4; ++nf) {
            const int nb = nw + nf * 16 + lk * 4;
            *reinterpret_cast<f32x4*>(&ot[m][nb]) = acc[mf][nf];
        }
    }
    __syncthreads();

    // 4096 16B-chunks / 512 thr = 8 iters. Per wave-instr: 64 lanes cover 64
    // consecutive 16B chunks of ONE row = 1KB contiguous store.
    #pragma unroll
    for (int j = 0; j < 8; ++j) {
        const int c   = j * 512 + t;
        const int row = c >> 7;          // 0..31 (4 complete rows per j)
        const int col = c & 127;         // 16B chunk within row
        const int n   = n0 + col * 4;
        if (n < E_TOT)                   // E%4==0 -> whole float4 valid
            *reinterpret_cast<float4*>(&out[(size_t)(m0 + row) * E_TOT + n]) =
                *reinterpret_cast<const float4*>(&ot[row][col * 4]);
    }
}

// ---------------------------------------------------------------------------
extern "C" void kernel_launch(void* const* d_in, const int* in_sizes, int n_in,
                              void* d_out, int out_size, void* d_ws, size_t ws_size,
                              hipStream_t stream) {
    const float* x  = (const float*)d_in[0];   // [4,128,768]
    const float* W  = (const float*)d_in[1];   // [256,768]
    const float* b  = (const float*)d_in[2];   // [256]
    const float* en = (const float*)d_in[3];   // [100000,256]
    float* out = (float*)d_out;                // [512,100000]

    unsigned short* qb = (unsigned short*)d_ws;                 // 256 KB
    unsigned short* eb = (unsigned short*)((char*)d_ws + (size_t)M_TOT * D_E * 2);

    prep_kernel<<<E_TOT / 32, 256, 0, stream>>>(en, eb);        // 3125 blocks
    proj_kernel<<<M_TOT / PTM, 256, 0, stream>>>(x, W, b, qb);  // 64 blocks
    sim_kernel<<<SIM_GRID, 512, 0, stream>>>(eb, qb, out);      // 3136 blocks
}

// Round 7
// 179.450 us; speedup vs baseline: 1.4306x; 1.4203x over previous
//
#include <hip/hip_runtime.h>
#include <hip/hip_bf16.h>

#define D_IN  768
#define D_E   256
#define M_TOT 512      // B*S
#define E_TOT 100000

typedef __attribute__((ext_vector_type(4))) float f32x4;
typedef __attribute__((ext_vector_type(8))) short bf16x8;

__device__ __forceinline__ unsigned short bf16bits(float f) {
    union { __hip_bfloat16 h; unsigned short u; } c;
    c.h = __float2bfloat16(f);
    return c.u;
}

__device__ __forceinline__ void gload_lds16(const void* g, void* l) {
    __builtin_amdgcn_global_load_lds(
        (const __attribute__((address_space(1))) void*)g,
        (__attribute__((address_space(3))) void*)l, 16, 0, 0);
}

// ---------------------------------------------------------------------------
// Kernel 0: eb[n][k] = bf16( en[n][k] / ||en[n]|| )   (~BW floor, 153 MB)
// ---------------------------------------------------------------------------
__global__ __launch_bounds__(256) void prep_kernel(
    const float* __restrict__ en, unsigned short* __restrict__ eb)
{
    const int lane = threadIdx.x & 63;
    const int gw   = blockIdx.x * 4 + (threadIdx.x >> 6);
    #pragma unroll 2
    for (int i = 0; i < 8; ++i) {
        const int row = gw * 8 + i;
        const float4 v = *reinterpret_cast<const float4*>(
            en + (size_t)row * D_E + lane * 4);
        float s = v.x*v.x + v.y*v.y + v.z*v.z + v.w*v.w;
        #pragma unroll
        for (int off = 1; off < 64; off <<= 1) s += __shfl_xor(s, off, 64);
        const float sc = 1.0f / fmaxf(sqrtf(s), 1e-8f);
        union { unsigned short u[4]; uint2 d; } o;
        o.u[0] = bf16bits(v.x * sc); o.u[1] = bf16bits(v.y * sc);
        o.u[2] = bf16bits(v.z * sc); o.u[3] = bf16bits(v.w * sc);
        *reinterpret_cast<uint2*>(eb + (size_t)row * D_E + lane * 4) = o.d;
    }
}

// ---------------------------------------------------------------------------
// Kernel 1: qb[m][e] = bf16( tanh(x@W^T + b) / ||row|| )
// ---------------------------------------------------------------------------
#define PTM 8
#define PBK 64
#define PROUNDS (D_IN / PBK)   // 12

__global__ __launch_bounds__(256) void proj_kernel(
    const float* __restrict__ x, const float* __restrict__ W,
    const float* __restrict__ b, unsigned short* __restrict__ qb)
{
    __shared__ float ws[D_E * (PBK + 1)];
    __shared__ float xs[PTM][PBK];
    __shared__ float red[PTM][4];

    const int t  = threadIdx.x;
    const int m0 = blockIdx.x * PTM;
    const int c4 = t & 15;
    const int rr = t >> 4;
    float4 wreg[16];
    float  xreg[2];
    float  acc[PTM];
    #pragma unroll
    for (int m = 0; m < PTM; ++m) acc[m] = 0.f;

    #pragma unroll
    for (int i = 0; i < 16; ++i)
        wreg[i] = *reinterpret_cast<const float4*>(
            &W[(size_t)(i * 16 + rr) * D_IN + c4 * 4]);
    #pragma unroll
    for (int i = 0; i < 2; ++i) {
        int f = i * 256 + t;
        xreg[i] = x[(size_t)(m0 + (f >> 6)) * D_IN + (f & 63)];
    }

    for (int rd = 0; rd < PROUNDS; ++rd) {
        #pragma unroll
        for (int i = 0; i < 16; ++i) {
            float* dst = &ws[(i * 16 + rr) * (PBK + 1) + c4 * 4];
            dst[0] = wreg[i].x; dst[1] = wreg[i].y;
            dst[2] = wreg[i].z; dst[3] = wreg[i].w;
        }
        #pragma unroll
        for (int i = 0; i < 2; ++i) {
            int f = i * 256 + t;
            xs[f >> 6][f & 63] = xreg[i];
        }
        __syncthreads();
        if (rd + 1 < PROUNDS) {
            const int k0 = (rd + 1) * PBK;
            #pragma unroll
            for (int i = 0; i < 16; ++i)
                wreg[i] = *reinterpret_cast<const float4*>(
                    &W[(size_t)(i * 16 + rr) * D_IN + k0 + c4 * 4]);
            #pragma unroll
            for (int i = 0; i < 2; ++i) {
                int f = i * 256 + t;
                xreg[i] = x[(size_t)(m0 + (f >> 6)) * D_IN + k0 + (f & 63)];
            }
        }
        #pragma unroll
        for (int k = 0; k < PBK; ++k) {
            float wv = ws[t * (PBK + 1) + k];
            #pragma unroll
            for (int m = 0; m < PTM; ++m)
                acc[m] = fmaf(xs[m][k], wv, acc[m]);
        }
        __syncthreads();
    }

    const int lane = t & 63, wid = t >> 6;
    const float bias = b[t];
    float q[PTM];
    #pragma unroll
    for (int m = 0; m < PTM; ++m) {
        q[m] = tanhf(acc[m] + bias);
        float s = q[m] * q[m];
        #pragma unroll
        for (int off = 1; off < 64; off <<= 1) s += __shfl_xor(s, off, 64);
        if (lane == 0) red[m][wid] = s;
    }
    __syncthreads();
    #pragma unroll
    for (int m = 0; m < PTM; ++m) {
        float s = red[m][0] + red[m][1] + red[m][2] + red[m][3];
        float qinv = 1.0f / fmaxf(sqrtf(s), 1e-8f);
        qb[(size_t)(m0 + m) * D_E + t] = bf16bits(q[m] * qinv);
    }
}

// ---------------------------------------------------------------------------
// Kernel 2 (v7): out[m][n] = qn[m] . en_hat[n] — PURE-LDS HOT LOOP (m97 shape)
// Block = 256 thr (4 waves of 64m x 32n), tile 128m x 64n, persistent over 25
// consecutive n-tiles. q tile (64 KB) staged to LDS ONCE per block; entity
// tiles double-buffered (2 x 32 KB) via global_load_lds + source pre-swizzle
// (refcheck-proven r3/r4). Inner loop: ds_read_b128 + MFMA only — no global
// loads the compiler can rematerialize. Stage-ahead 2-phase pipeline, one
// barrier per tile. Grid = 252 (~1 block/CU, LDS 128 KB).
// ---------------------------------------------------------------------------
#define BM 128
#define BN 64
#define TPB 25                         // n-tiles per block
#define NGRPN 63                       // 63*25*64 = 100800 >= 100000
#define SIM_GRID (NGRPN * (M_TOT / BM))   // 252

__global__ __launch_bounds__(256, 2) void sim_kernel(
    const unsigned short* __restrict__ eb, const unsigned short* __restrict__ qb,
    float* __restrict__ out)
{
    __shared__ unsigned short qs[BM * D_E];       // 64 KB
    __shared__ unsigned short es[2][BN * D_E];    // 2 x 32 KB

    const int t    = threadIdx.x;
    const int lane = t & 63;
    const int wid  = t >> 6;        // 0..3
    const int l15  = lane & 15;
    const int lk   = lane >> 4;     // 0..3
    const int wm   = (wid >> 1) * 64;
    const int wn   = (wid & 1) * 32;

    // bijective chunked XCD swizzle (m204): 4 consecutive vbids = the 4
    // m-blocks of one n-group -> same XCD -> entity tile L2 shared.
    int vbid;
    {
        const int q = SIM_GRID >> 3, r = SIM_GRID & 7;   // 31, 4
        const int xcd = blockIdx.x & 7, rk = blockIdx.x >> 3;
        vbid = (xcd < r ? xcd * (q + 1) : r * (q + 1) + (xcd - r) * q) + rk;
    }
    const int mg    = vbid & 3;
    const int ngrp  = vbid >> 2;            // 0..62
    const int m0    = mg * BM;
    const int nbase = ngrp * (TPB * BN);    // ngrp * 1600

    // ---- stage q tile once: 4096 x 16B chunks, source pre-swizzled ----
    #pragma unroll
    for (int i = 0; i < 16; ++i) {
        const int c   = i * 256 + t;
        const int row = c >> 5;             // 0..127
        const int c16 = c & 31;
        const unsigned short* src =
            qb + (size_t)(m0 + row) * D_E + ((c16 ^ (row & 7)) << 3);
        gload_lds16(src, (void*)&qs[(size_t)c << 3]);
    }
    // ---- stage entity tile 0 into buf 0 ----
    #pragma unroll
    for (int i = 0; i < 8; ++i) {
        const int c   = i * 256 + t;
        const int row = c >> 5;             // 0..63
        const int c16 = c & 31;
        int rg = nbase + row; if (rg >= E_TOT) rg = E_TOT - 1;
        const unsigned short* src =
            eb + (size_t)rg * D_E + ((c16 ^ (row & 7)) << 3);
        gload_lds16(src, (void*)&es[0][(size_t)c << 3]);
    }
    __syncthreads();   // compiler emits vmcnt(0) drain before barrier

    const char* qsb = reinterpret_cast<const char*>(qs);

    for (int tt = 0; tt < TPB; ++tt) {
        const int n0 = nbase + tt * BN;
        if (n0 >= E_TOT) break;             // block-uniform
        const int cur = tt & 1;

        // stage-ahead: issue next tile's loads into the other buffer
        const int nn0 = n0 + BN;
        if (tt + 1 < TPB && nn0 < E_TOT) {
            #pragma unroll
            for (int i = 0; i < 8; ++i) {
                const int c   = i * 256 + t;
                const int row = c >> 5;
                const int c16 = c & 31;
                int rg = nn0 + row; if (rg >= E_TOT) rg = E_TOT - 1;
                const unsigned short* src =
                    eb + (size_t)rg * D_E + ((c16 ^ (row & 7)) << 3);
                gload_lds16(src, (void*)&es[cur ^ 1][(size_t)c << 3]);
            }
        }

        const char* esb = reinterpret_cast<const char*>(&es[cur][0]);

        f32x4 acc[4][2];
        #pragma unroll
        for (int mf = 0; mf < 4; ++mf)
            #pragma unroll
            for (int nf = 0; nf < 2; ++nf)
                acc[mf][nf] = (f32x4){0.f, 0.f, 0.f, 0.f};

        #pragma unroll
        for (int ks = 0; ks < 8; ++ks) {
            const int kb = ks * 64 + lk * 16;
            bf16x8 ef[2];
            #pragma unroll
            for (int nf = 0; nf < 2; ++nf) {
                const int row = wn + nf * 16 + l15;
                const int cb  = kb ^ ((row & 7) << 4);
                ef[nf] = *reinterpret_cast<const bf16x8*>(esb + row * 512 + cb);
            }
            #pragma unroll
            for (int mf = 0; mf < 4; ++mf) {
                const int rq  = wm + mf * 16 + l15;
                const int cbq = kb ^ ((rq & 7) << 4);
                const bf16x8 qf =
                    *reinterpret_cast<const bf16x8*>(qsb + rq * 512 + cbq);
                acc[mf][0] = __builtin_amdgcn_mfma_f32_16x16x32_bf16(
                    ef[0], qf, acc[mf][0], 0, 0, 0);
                acc[mf][1] = __builtin_amdgcn_mfma_f32_16x16x32_bf16(
                    ef[1], qf, acc[mf][1], 0, 0, 0);
            }
        }

        // per-tile stores straight from acc (r6 proved store shape is neutral)
        #pragma unroll
        for (int mf = 0; mf < 4; ++mf) {
            const int m = m0 + wm + mf * 16 + l15;
            #pragma unroll
            for (int nf = 0; nf < 2; ++nf) {
                const int n = n0 + wn + nf * 16 + lk * 4;
                if (n < E_TOT)     // E%4==0 -> whole f32x4 valid
                    *reinterpret_cast<f32x4*>(&out[(size_t)m * E_TOT + n]) =
                        acc[mf][nf];
            }
        }

        __syncthreads();   // drains stage loads (vmcnt 0) + all waves done
    }
}

// ---------------------------------------------------------------------------
extern "C" void kernel_launch(void* const* d_in, const int* in_sizes, int n_in,
                              void* d_out, int out_size, void* d_ws, size_t ws_size,
                              hipStream_t stream) {
    const float* x  = (const float*)d_in[0];   // [4,128,768]
    const float* W  = (const float*)d_in[1];   // [256,768]
    const float* b  = (const float*)d_in[2];   // [256]
    const float* en = (const float*)d_in[3];   // [100000,256]
    float* out = (float*)d_out;                // [512,100000]

    unsigned short* qb = (unsigned short*)d_ws;                 // 256 KB
    unsigned short* eb = (unsigned short*)((char*)d_ws + (size_t)M_TOT * D_E * 2);

    prep_kernel<<<E_TOT / 32, 256, 0, stream>>>(en, eb);        // 3125 blocks
    proj_kernel<<<M_TOT / PTM, 256, 0, stream>>>(x, W, b, qb);  // 64 blocks
    sim_kernel<<<SIM_GRID, 256, 0, stream>>>(eb, qb, out);      // 252 blocks
}

// Round 8
// 175.862 us; speedup vs baseline: 1.4598x; 1.0204x over previous
//
#include <hip/hip_runtime.h>
#include <hip/hip_bf16.h>

#define D_IN  768
#define D_E   256
#define M_TOT 512      // B*S
#define E_TOT 100000

typedef __attribute__((ext_vector_type(4))) float f32x4;
typedef __attribute__((ext_vector_type(8))) short bf16x8;

__device__ __forceinline__ unsigned short bf16bits(float f) {
    union { __hip_bfloat16 h; unsigned short u; } c;
    c.h = __float2bfloat16(f);
    return c.u;
}

__device__ __forceinline__ void gload_lds16(const void* g, void* l) {
    __builtin_amdgcn_global_load_lds(
        (const __attribute__((address_space(1))) void*)g,
        (__attribute__((address_space(3))) void*)l, 16, 0, 0);
}

// ---------------------------------------------------------------------------
// Kernel 0: eb[n][k] = bf16( en[n][k] / ||en[n]|| )   (~BW floor, 153 MB)
// ---------------------------------------------------------------------------
__global__ __launch_bounds__(256) void prep_kernel(
    const float* __restrict__ en, unsigned short* __restrict__ eb)
{
    const int lane = threadIdx.x & 63;
    const int gw   = blockIdx.x * 4 + (threadIdx.x >> 6);
    #pragma unroll 2
    for (int i = 0; i < 8; ++i) {
        const int row = gw * 8 + i;
        const float4 v = *reinterpret_cast<const float4*>(
            en + (size_t)row * D_E + lane * 4);
        float s = v.x*v.x + v.y*v.y + v.z*v.z + v.w*v.w;
        #pragma unroll
        for (int off = 1; off < 64; off <<= 1) s += __shfl_xor(s, off, 64);
        const float sc = 1.0f / fmaxf(sqrtf(s), 1e-8f);
        union { unsigned short u[4]; uint2 d; } o;
        o.u[0] = bf16bits(v.x * sc); o.u[1] = bf16bits(v.y * sc);
        o.u[2] = bf16bits(v.z * sc); o.u[3] = bf16bits(v.w * sc);
        *reinterpret_cast<uint2*>(eb + (size_t)row * D_E + lane * 4) = o.d;
    }
}

// ---------------------------------------------------------------------------
// Kernel 1: qb[m][e] = bf16( tanh(x@W^T + b) / ||row|| )
// ---------------------------------------------------------------------------
#define PTM 8
#define PBK 64
#define PROUNDS (D_IN / PBK)   // 12

__global__ __launch_bounds__(256) void proj_kernel(
    const float* __restrict__ x, const float* __restrict__ W,
    const float* __restrict__ b, unsigned short* __restrict__ qb)
{
    __shared__ float ws[D_E * (PBK + 1)];
    __shared__ float xs[PTM][PBK];
    __shared__ float red[PTM][4];

    const int t  = threadIdx.x;
    const int m0 = blockIdx.x * PTM;
    const int c4 = t & 15;
    const int rr = t >> 4;
    float4 wreg[16];
    float  xreg[2];
    float  acc[PTM];
    #pragma unroll
    for (int m = 0; m < PTM; ++m) acc[m] = 0.f;

    #pragma unroll
    for (int i = 0; i < 16; ++i)
        wreg[i] = *reinterpret_cast<const float4*>(
            &W[(size_t)(i * 16 + rr) * D_IN + c4 * 4]);
    #pragma unroll
    for (int i = 0; i < 2; ++i) {
        int f = i * 256 + t;
        xreg[i] = x[(size_t)(m0 + (f >> 6)) * D_IN + (f & 63)];
    }

    for (int rd = 0; rd < PROUNDS; ++rd) {
        #pragma unroll
        for (int i = 0; i < 16; ++i) {
            float* dst = &ws[(i * 16 + rr) * (PBK + 1) + c4 * 4];
            dst[0] = wreg[i].x; dst[1] = wreg[i].y;
            dst[2] = wreg[i].z; dst[3] = wreg[i].w;
        }
        #pragma unroll
        for (int i = 0; i < 2; ++i) {
            int f = i * 256 + t;
            xs[f >> 6][f & 63] = xreg[i];
        }
        __syncthreads();
        if (rd + 1 < PROUNDS) {
            const int k0 = (rd + 1) * PBK;
            #pragma unroll
            for (int i = 0; i < 16; ++i)
                wreg[i] = *reinterpret_cast<const float4*>(
                    &W[(size_t)(i * 16 + rr) * D_IN + k0 + c4 * 4]);
            #pragma unroll
            for (int i = 0; i < 2; ++i) {
                int f = i * 256 + t;
                xreg[i] = x[(size_t)(m0 + (f >> 6)) * D_IN + k0 + (f & 63)];
            }
        }
        #pragma unroll
        for (int k = 0; k < PBK; ++k) {
            float wv = ws[t * (PBK + 1) + k];
            #pragma unroll
            for (int m = 0; m < PTM; ++m)
                acc[m] = fmaf(xs[m][k], wv, acc[m]);
        }
        __syncthreads();
    }

    const int lane = t & 63, wid = t >> 6;
    const float bias = b[t];
    float q[PTM];
    #pragma unroll
    for (int m = 0; m < PTM; ++m) {
        q[m] = tanhf(acc[m] + bias);
        float s = q[m] * q[m];
        #pragma unroll
        for (int off = 1; off < 64; off <<= 1) s += __shfl_xor(s, off, 64);
        if (lane == 0) red[m][wid] = s;
    }
    __syncthreads();
    #pragma unroll
    for (int m = 0; m < PTM; ++m) {
        float s = red[m][0] + red[m][1] + red[m][2] + red[m][3];
        float qinv = 1.0f / fmaxf(sqrtf(s), 1e-8f);
        qb[(size_t)(m0 + m) * D_E + t] = bf16bits(q[m] * qinv);
    }
}

// ---------------------------------------------------------------------------
// Kernel 2 (v8): same pure-LDS compute core as v7 (swizzled q/e tiles,
// refcheck-proven), restructured for overlap:
//  * 8 waves/block (512 thr), wave tile 32m x 32n over 128m x 64n block
//    -> 2 waves/SIMD (v7 had 1): ds_read latency + barrier drains now hidden
//    by the co-resident wave.
//  * stores issued AFTER the barrier: tile tt's stores retire during tile
//    tt+1's whole compute phase instead of inside the per-tile vmcnt(0) drain.
//  * grid 252 = 63 n-groups x 4 m-groups, TPB=25 tiles/block, q staged once.
// ---------------------------------------------------------------------------
#define BM 128
#define BN 64
#define TPB 25
#define NGRPN 63                        // 63*25*64 = 100800 >= 100000
#define SIM_GRID (NGRPN * (M_TOT / BM))   // 252

__global__ __launch_bounds__(512, 2) void sim_kernel(
    const unsigned short* __restrict__ eb, const unsigned short* __restrict__ qb,
    float* __restrict__ out)
{
    __shared__ unsigned short qs[BM * D_E];       // 64 KB
    __shared__ unsigned short es[2][BN * D_E];    // 2 x 32 KB

    const int t    = threadIdx.x;
    const int lane = t & 63;
    const int wid  = t >> 6;        // 0..7
    const int l15  = lane & 15;
    const int lk   = lane >> 4;     // 0..3
    const int wm   = (wid >> 1) * 32;   // 0,32,64,96
    const int wn   = (wid & 1) * 32;    // 0,32

    // bijective chunked XCD swizzle (m204): the 4 m-blocks of one n-group
    // are virtually consecutive -> same XCD -> entity tiles L2-shared.
    int vbid;
    {
        const int q = SIM_GRID >> 3, r = SIM_GRID & 7;   // 31, 4
        const int xcd = blockIdx.x & 7, rk = blockIdx.x >> 3;
        vbid = (xcd < r ? xcd * (q + 1) : r * (q + 1) + (xcd - r) * q) + rk;
    }
    const int mg    = vbid & 3;
    const int ngrp  = vbid >> 2;            // 0..62
    const int m0    = mg * BM;
    const int nbase = ngrp * (TPB * BN);    // ngrp * 1600

    // ---- stage q tile once: 4096 x 16B chunks / 512 thr ----
    #pragma unroll
    for (int i = 0; i < 8; ++i) {
        const int c   = i * 512 + t;
        const int row = c >> 5;             // 0..127
        const int c16 = c & 31;
        const unsigned short* src =
            qb + (size_t)(m0 + row) * D_E + ((c16 ^ (row & 7)) << 3);
        gload_lds16(src, (void*)&qs[(size_t)c << 3]);
    }
    // ---- stage entity tile 0 into buf 0: 2048 chunks / 512 thr ----
    #pragma unroll
    for (int i = 0; i < 4; ++i) {
        const int c   = i * 512 + t;
        const int row = c >> 5;             // 0..63
        const int c16 = c & 31;
        int rg = nbase + row; if (rg >= E_TOT) rg = E_TOT - 1;
        const unsigned short* src =
            eb + (size_t)rg * D_E + ((c16 ^ (row & 7)) << 3);
        gload_lds16(src, (void*)&es[0][(size_t)c << 3]);
    }
    __syncthreads();   // drains stage loads (compiler vmcnt(0) before barrier)

    const char* qsb = reinterpret_cast<const char*>(qs);

    for (int tt = 0; tt < TPB; ++tt) {
        const int n0 = nbase + tt * BN;
        if (n0 >= E_TOT) break;             // block-uniform
        const int cur = tt & 1;

        // stage-ahead next tile into the other buffer (drained at barrier)
        const int nn0 = n0 + BN;
        if (tt + 1 < TPB && nn0 < E_TOT) {
            #pragma unroll
            for (int i = 0; i < 4; ++i) {
                const int c   = i * 512 + t;
                const int row = c >> 5;
                const int c16 = c & 31;
                int rg = nn0 + row; if (rg >= E_TOT) rg = E_TOT - 1;
                const unsigned short* src =
                    eb + (size_t)rg * D_E + ((c16 ^ (row & 7)) << 3);
                gload_lds16(src, (void*)&es[cur ^ 1][(size_t)c << 3]);
            }
        }

        const char* esb = reinterpret_cast<const char*>(&es[cur][0]);

        f32x4 acc[2][2];
        #pragma unroll
        for (int mf = 0; mf < 2; ++mf)
            #pragma unroll
            for (int nf = 0; nf < 2; ++nf)
                acc[mf][nf] = (f32x4){0.f, 0.f, 0.f, 0.f};

        #pragma unroll
        for (int ks = 0; ks < 8; ++ks) {
            const int kb = ks * 64 + lk * 16;
            bf16x8 ef[2];
            #pragma unroll
            for (int nf = 0; nf < 2; ++nf) {
                const int row = wn + nf * 16 + l15;
                const int cb  = kb ^ ((row & 7) << 4);
                ef[nf] = *reinterpret_cast<const bf16x8*>(esb + row * 512 + cb);
            }
            #pragma unroll
            for (int mf = 0; mf < 2; ++mf) {
                const int rq  = wm + mf * 16 + l15;
                const int cbq = kb ^ ((rq & 7) << 4);
                const bf16x8 qf =
                    *reinterpret_cast<const bf16x8*>(qsb + rq * 512 + cbq);
                acc[mf][0] = __builtin_amdgcn_mfma_f32_16x16x32_bf16(
                    ef[0], qf, acc[mf][0], 0, 0, 0);
                acc[mf][1] = __builtin_amdgcn_mfma_f32_16x16x32_bf16(
                    ef[1], qf, acc[mf][1], 0, 0, 0);
            }
        }

        __syncthreads();   // drains next-tile stage; all waves done with cur

        // stores AFTER the barrier: retire during next tile's compute phase
        #pragma unroll
        for (int mf = 0; mf < 2; ++mf) {
            const int m = m0 + wm + mf * 16 + l15;
            #pragma unroll
            for (int nf = 0; nf < 2; ++nf) {
                const int n = n0 + wn + nf * 16 + lk * 4;
                if (n < E_TOT)     // E%4==0 -> whole f32x4 valid
                    *reinterpret_cast<f32x4*>(&out[(size_t)m * E_TOT + n]) =
                        acc[mf][nf];
            }
        }
    }
}

// ---------------------------------------------------------------------------
extern "C" void kernel_launch(void* const* d_in, const int* in_sizes, int n_in,
                              void* d_out, int out_size, void* d_ws, size_t ws_size,
                              hipStream_t stream) {
    const float* x  = (const float*)d_in[0];   // [4,128,768]
    const float* W  = (const float*)d_in[1];   // [256,768]
    const float* b  = (const float*)d_in[2];   // [256]
    const float* en = (const float*)d_in[3];   // [100000,256]
    float* out = (float*)d_out;                // [512,100000]

    unsigned short* qb = (unsigned short*)d_ws;                 // 256 KB
    unsigned short* eb = (unsigned short*)((char*)d_ws + (size_t)M_TOT * D_E * 2);

    prep_kernel<<<E_TOT / 32, 256, 0, stream>>>(en, eb);        // 3125 blocks
    proj_kernel<<<M_TOT / PTM, 256, 0, stream>>>(x, W, b, qb);  // 64 blocks
    sim_kernel<<<SIM_GRID, 512, 0, stream>>>(eb, qb, out);      // 252 blocks
}

// Round 9
// 141.455 us; speedup vs baseline: 1.8148x; 1.2432x over previous
//
#include <hip/hip_runtime.h>
#include <hip/hip_bf16.h>

#define D_IN  768
#define D_E   256
#define M_TOT 512      // B*S
#define E_TOT 100000

typedef __attribute__((ext_vector_type(4))) float f32x4;
typedef __attribute__((ext_vector_type(8))) short bf16x8;

__device__ __forceinline__ unsigned short bf16bits(float f) {
    union { __hip_bfloat16 h; unsigned short u; } c;
    c.h = __float2bfloat16(f);
    return c.u;
}

__device__ __forceinline__ void gload_lds16(const void* g, void* l) {
    __builtin_amdgcn_global_load_lds(
        (const __attribute__((address_space(1))) void*)g,
        (__attribute__((address_space(3))) void*)l, 16, 0, 0);
}

// ---------------------------------------------------------------------------
// Fused prep+proj (independent work, one launch -> concurrent execution):
//   blocks [0,64):    proj  qb[m][e] = bf16(tanh(x@W^T+b)/||row||), 512 thr
//   blocks [64,1627): prep  eb[n][k] = bf16(en[n][k]/||en[n]||),    512 thr
// ---------------------------------------------------------------------------
#define PROJ_BLOCKS 64
#define PREP_BLOCKS 1563                 // 1563*64 = 100032 >= 100000
#define PP_GRID (PROJ_BLOCKS + PREP_BLOCKS)
#define PTM 8
#define PBK 64
#define PROUNDS (D_IN / PBK)             // 12

__global__ __launch_bounds__(512) void fused_pp(
    const float* __restrict__ x, const float* __restrict__ W,
    const float* __restrict__ b, const float* __restrict__ en,
    unsigned short* __restrict__ qb, unsigned short* __restrict__ eb)
{
    __shared__ float ws[D_E * (PBK + 1)];   // 65 KB (proj only)
    __shared__ float xs[PTM][PBK];
    __shared__ float red[PTM][4];
    __shared__ float qiv[PTM];

    const int t   = threadIdx.x;
    const int bid = blockIdx.x;

    if (bid >= PROJ_BLOCKS) {
        // ---------------- prep: 8 waves x 8 rows ----------------
        const int lane = t & 63;
        const int gw   = (bid - PROJ_BLOCKS) * 8 + (t >> 6);
        #pragma unroll 2
        for (int i = 0; i < 8; ++i) {
            const int row = gw * 8 + i;
            if (row >= E_TOT) break;
            const float4 v = *reinterpret_cast<const float4*>(
                en + (size_t)row * D_E + lane * 4);
            float s = v.x*v.x + v.y*v.y + v.z*v.z + v.w*v.w;
            #pragma unroll
            for (int off = 1; off < 64; off <<= 1) s += __shfl_xor(s, off, 64);
            const float sc = 1.0f / fmaxf(sqrtf(s), 1e-8f);
            union { unsigned short u[4]; uint2 d; } o;
            o.u[0] = bf16bits(v.x * sc); o.u[1] = bf16bits(v.y * sc);
            o.u[2] = bf16bits(v.z * sc); o.u[3] = bf16bits(v.w * sc);
            *reinterpret_cast<uint2*>(eb + (size_t)row * D_E + lane * 4) = o.d;
        }
        return;
    }

    // ---------------- proj: 512 thr, thread = (e, m-half of 4) ----------------
    const int m0   = bid * PTM;
    const int e    = t & 255;
    const int half = t >> 8;          // 0/1 -> m = half*4 + j
    const int c4   = t & 15;          // W-stage: float4 column
    const int rr   = t >> 4;          // W-stage: row subgroup (0..31)

    float4 wreg[8];
    float  xreg = 0.f;
    float  acc[4] = {0.f, 0.f, 0.f, 0.f};

    #pragma unroll
    for (int i = 0; i < 8; ++i)
        wreg[i] = *reinterpret_cast<const float4*>(
            &W[(size_t)(i * 32 + rr) * D_IN + c4 * 4]);
    xreg = x[(size_t)(m0 + (t >> 6)) * D_IN + (t & 63)];

    for (int rd = 0; rd < PROUNDS; ++rd) {
        #pragma unroll
        for (int i = 0; i < 8; ++i) {
            float* dst = &ws[(i * 32 + rr) * (PBK + 1) + c4 * 4];
            dst[0] = wreg[i].x; dst[1] = wreg[i].y;
            dst[2] = wreg[i].z; dst[3] = wreg[i].w;
        }
        xs[t >> 6][t & 63] = xreg;
        __syncthreads();
        if (rd + 1 < PROUNDS) {
            const int k0 = (rd + 1) * PBK;
            #pragma unroll
            for (int i = 0; i < 8; ++i)
                wreg[i] = *reinterpret_cast<const float4*>(
                    &W[(size_t)(i * 32 + rr) * D_IN + k0 + c4 * 4]);
            xreg = x[(size_t)(m0 + (t >> 6)) * D_IN + k0 + (t & 63)];
        }
        #pragma unroll
        for (int k = 0; k < PBK; ++k) {
            const float wv = ws[e * (PBK + 1) + k];
            #pragma unroll
            for (int j = 0; j < 4; ++j)
                acc[j] = fmaf(xs[half * 4 + j][k], wv, acc[j]);
        }
        __syncthreads();
    }

    const float bias = b[e];
    const int wv4 = (t >> 6) & 3;     // wave within half
    const int lane = t & 63;
    float q[4];
    #pragma unroll
    for (int j = 0; j < 4; ++j) {
        q[j] = tanhf(acc[j] + bias);
        float s = q[j] * q[j];
        #pragma unroll
        for (int off = 1; off < 64; off <<= 1) s += __shfl_xor(s, off, 64);
        if (lane == 0) red[half * 4 + j][wv4] = s;
    }
    __syncthreads();
    if (t < PTM) {
        const float s = red[t][0] + red[t][1] + red[t][2] + red[t][3];
        qiv[t] = 1.0f / fmaxf(sqrtf(s), 1e-8f);
    }
    __syncthreads();
    #pragma unroll
    for (int j = 0; j < 4; ++j)
        qb[(size_t)(m0 + half * 4 + j) * D_E + e] =
            bf16bits(q[j] * qiv[half * 4 + j]);
}

// ---------------------------------------------------------------------------
// Kernel 2 (v8, UNCHANGED): pure-LDS hot loop, 8 waves, dbuf entity tiles,
// q tile staged once, stores after the barrier. Verbatim from round 8.
// ---------------------------------------------------------------------------
#define BM 128
#define BN 64
#define TPB 25
#define NGRPN 63                        // 63*25*64 = 100800 >= 100000
#define SIM_GRID (NGRPN * (M_TOT / BM))   // 252

__global__ __launch_bounds__(512, 2) void sim_kernel(
    const unsigned short* __restrict__ eb, const unsigned short* __restrict__ qb,
    float* __restrict__ out)
{
    __shared__ unsigned short qs[BM * D_E];       // 64 KB
    __shared__ unsigned short es[2][BN * D_E];    // 2 x 32 KB

    const int t    = threadIdx.x;
    const int lane = t & 63;
    const int wid  = t >> 6;        // 0..7
    const int l15  = lane & 15;
    const int lk   = lane >> 4;     // 0..3
    const int wm   = (wid >> 1) * 32;   // 0,32,64,96
    const int wn   = (wid & 1) * 32;    // 0,32

    int vbid;
    {
        const int q = SIM_GRID >> 3, r = SIM_GRID & 7;   // 31, 4
        const int xcd = blockIdx.x & 7, rk = blockIdx.x >> 3;
        vbid = (xcd < r ? xcd * (q + 1) : r * (q + 1) + (xcd - r) * q) + rk;
    }
    const int mg    = vbid & 3;
    const int ngrp  = vbid >> 2;            // 0..62
    const int m0    = mg * BM;
    const int nbase = ngrp * (TPB * BN);    // ngrp * 1600

    #pragma unroll
    for (int i = 0; i < 8; ++i) {
        const int c   = i * 512 + t;
        const int row = c >> 5;             // 0..127
        const int c16 = c & 31;
        const unsigned short* src =
            qb + (size_t)(m0 + row) * D_E + ((c16 ^ (row & 7)) << 3);
        gload_lds16(src, (void*)&qs[(size_t)c << 3]);
    }
    #pragma unroll
    for (int i = 0; i < 4; ++i) {
        const int c   = i * 512 + t;
        const int row = c >> 5;             // 0..63
        const int c16 = c & 31;
        int rg = nbase + row; if (rg >= E_TOT) rg = E_TOT - 1;
        const unsigned short* src =
            eb + (size_t)rg * D_E + ((c16 ^ (row & 7)) << 3);
        gload_lds16(src, (void*)&es[0][(size_t)c << 3]);
    }
    __syncthreads();

    const char* qsb = reinterpret_cast<const char*>(qs);

    for (int tt = 0; tt < TPB; ++tt) {
        const int n0 = nbase + tt * BN;
        if (n0 >= E_TOT) break;             // block-uniform
        const int cur = tt & 1;

        const int nn0 = n0 + BN;
        if (tt + 1 < TPB && nn0 < E_TOT) {
            #pragma unroll
            for (int i = 0; i < 4; ++i) {
                const int c   = i * 512 + t;
                const int row = c >> 5;
                const int c16 = c & 31;
                int rg = nn0 + row; if (rg >= E_TOT) rg = E_TOT - 1;
                const unsigned short* src =
                    eb + (size_t)rg * D_E + ((c16 ^ (row & 7)) << 3);
                gload_lds16(src, (void*)&es[cur ^ 1][(size_t)c << 3]);
            }
        }

        const char* esb = reinterpret_cast<const char*>(&es[cur][0]);

        f32x4 acc[2][2];
        #pragma unroll
        for (int mf = 0; mf < 2; ++mf)
            #pragma unroll
            for (int nf = 0; nf < 2; ++nf)
                acc[mf][nf] = (f32x4){0.f, 0.f, 0.f, 0.f};

        #pragma unroll
        for (int ks = 0; ks < 8; ++ks) {
            const int kb = ks * 64 + lk * 16;
            bf16x8 ef[2];
            #pragma unroll
            for (int nf = 0; nf < 2; ++nf) {
                const int row = wn + nf * 16 + l15;
                const int cb  = kb ^ ((row & 7) << 4);
                ef[nf] = *reinterpret_cast<const bf16x8*>(esb + row * 512 + cb);
            }
            #pragma unroll
            for (int mf = 0; mf < 2; ++mf) {
                const int rq  = wm + mf * 16 + l15;
                const int cbq = kb ^ ((rq & 7) << 4);
                const bf16x8 qf =
                    *reinterpret_cast<const bf16x8*>(qsb + rq * 512 + cbq);
                acc[mf][0] = __builtin_amdgcn_mfma_f32_16x16x32_bf16(
                    ef[0], qf, acc[mf][0], 0, 0, 0);
                acc[mf][1] = __builtin_amdgcn_mfma_f32_16x16x32_bf16(
                    ef[1], qf, acc[mf][1], 0, 0, 0);
            }
        }

        __syncthreads();

        #pragma unroll
        for (int mf = 0; mf < 2; ++mf) {
            const int m = m0 + wm + mf * 16 + l15;
            #pragma unroll
            for (int nf = 0; nf < 2; ++nf) {
                const int n = n0 + wn + nf * 16 + lk * 4;
                if (n < E_TOT)
                    *reinterpret_cast<f32x4*>(&out[(size_t)m * E_TOT + n]) =
                        acc[mf][nf];
            }
        }
    }
}

// ---------------------------------------------------------------------------
extern "C" void kernel_launch(void* const* d_in, const int* in_sizes, int n_in,
                              void* d_out, int out_size, void* d_ws, size_t ws_size,
                              hipStream_t stream) {
    const float* x  = (const float*)d_in[0];   // [4,128,768]
    const float* W  = (const float*)d_in[1];   // [256,768]
    const float* b  = (const float*)d_in[2];   // [256]
    const float* en = (const float*)d_in[3];   // [100000,256]
    float* out = (float*)d_out;                // [512,100000]

    unsigned short* qb = (unsigned short*)d_ws;                 // 256 KB
    unsigned short* eb = (unsigned short*)((char*)d_ws + (size_t)M_TOT * D_E * 2);

    fused_pp<<<PP_GRID, 512, 0, stream>>>(x, W, b, en, qb, eb); // 1627 blocks
    sim_kernel<<<SIM_GRID, 512, 0, stream>>>(eb, qb, out);      // 252 blocks
}

// Round 10
// 133.494 us; speedup vs baseline: 1.9231x; 1.0596x over previous
//
#include <hip/hip_runtime.h>
#include <hip/hip_bf16.h>

#define D_IN  768
#define D_E   256
#define M_TOT 512      // B*S
#define E_TOT 100000

typedef __attribute__((ext_vector_type(4))) float f32x4;
typedef __attribute__((ext_vector_type(8))) short bf16x8;

__device__ __forceinline__ unsigned short bf16bits(float f) {
    union { __hip_bfloat16 h; unsigned short u; } c;
    c.h = __float2bfloat16(f);
    return c.u;
}

__device__ __forceinline__ void gload_lds16(const void* g, void* l) {
    __builtin_amdgcn_global_load_lds(
        (const __attribute__((address_space(1))) void*)g,
        (__attribute__((address_space(3))) void*)l, 16, 0, 0);
}

// ---------------------------------------------------------------------------
// Fused prep+proj (unchanged from round 9 — at BW floor):
//   blocks [0,64):    proj  qb[m][e] = bf16(tanh(x@W^T+b)/||row||)
//   blocks [64,1627): prep  eb[n][k] = bf16(en[n][k]/||en[n]||)
// ---------------------------------------------------------------------------
#define PROJ_BLOCKS 64
#define PREP_BLOCKS 1563                 // 1563*64 = 100032 >= 100000
#define PP_GRID (PROJ_BLOCKS + PREP_BLOCKS)
#define PTM 8
#define PBK 64
#define PROUNDS (D_IN / PBK)             // 12

__global__ __launch_bounds__(512) void fused_pp(
    const float* __restrict__ x, const float* __restrict__ W,
    const float* __restrict__ b, const float* __restrict__ en,
    unsigned short* __restrict__ qb, unsigned short* __restrict__ eb)
{
    __shared__ float ws[D_E * (PBK + 1)];   // 65 KB (proj only)
    __shared__ float xs[PTM][PBK];
    __shared__ float red[PTM][4];
    __shared__ float qiv[PTM];

    const int t   = threadIdx.x;
    const int bid = blockIdx.x;

    if (bid >= PROJ_BLOCKS) {
        const int lane = t & 63;
        const int gw   = (bid - PROJ_BLOCKS) * 8 + (t >> 6);
        #pragma unroll 2
        for (int i = 0; i < 8; ++i) {
            const int row = gw * 8 + i;
            if (row >= E_TOT) break;
            const float4 v = *reinterpret_cast<const float4*>(
                en + (size_t)row * D_E + lane * 4);
            float s = v.x*v.x + v.y*v.y + v.z*v.z + v.w*v.w;
            #pragma unroll
            for (int off = 1; off < 64; off <<= 1) s += __shfl_xor(s, off, 64);
            const float sc = 1.0f / fmaxf(sqrtf(s), 1e-8f);
            union { unsigned short u[4]; uint2 d; } o;
            o.u[0] = bf16bits(v.x * sc); o.u[1] = bf16bits(v.y * sc);
            o.u[2] = bf16bits(v.z * sc); o.u[3] = bf16bits(v.w * sc);
            *reinterpret_cast<uint2*>(eb + (size_t)row * D_E + lane * 4) = o.d;
        }
        return;
    }

    const int m0   = bid * PTM;
    const int e    = t & 255;
    const int half = t >> 8;
    const int c4   = t & 15;
    const int rr   = t >> 4;

    float4 wreg[8];
    float  xreg = 0.f;
    float  acc[4] = {0.f, 0.f, 0.f, 0.f};

    #pragma unroll
    for (int i = 0; i < 8; ++i)
        wreg[i] = *reinterpret_cast<const float4*>(
            &W[(size_t)(i * 32 + rr) * D_IN + c4 * 4]);
    xreg = x[(size_t)(m0 + (t >> 6)) * D_IN + (t & 63)];

    for (int rd = 0; rd < PROUNDS; ++rd) {
        #pragma unroll
        for (int i = 0; i < 8; ++i) {
            float* dst = &ws[(i * 32 + rr) * (PBK + 1) + c4 * 4];
            dst[0] = wreg[i].x; dst[1] = wreg[i].y;
            dst[2] = wreg[i].z; dst[3] = wreg[i].w;
        }
        xs[t >> 6][t & 63] = xreg;
        __syncthreads();
        if (rd + 1 < PROUNDS) {
            const int k0 = (rd + 1) * PBK;
            #pragma unroll
            for (int i = 0; i < 8; ++i)
                wreg[i] = *reinterpret_cast<const float4*>(
                    &W[(size_t)(i * 32 + rr) * D_IN + k0 + c4 * 4]);
            xreg = x[(size_t)(m0 + (t >> 6)) * D_IN + k0 + (t & 63)];
        }
        #pragma unroll
        for (int k = 0; k < PBK; ++k) {
            const float wv = ws[e * (PBK + 1) + k];
            #pragma unroll
            for (int j = 0; j < 4; ++j)
                acc[j] = fmaf(xs[half * 4 + j][k], wv, acc[j]);
        }
        __syncthreads();
    }

    const float bias = b[e];
    const int wv4 = (t >> 6) & 3;
    const int lane = t & 63;
    float q[4];
    #pragma unroll
    for (int j = 0; j < 4; ++j) {
        q[j] = tanhf(acc[j] + bias);
        float s = q[j] * q[j];
        #pragma unroll
        for (int off = 1; off < 64; off <<= 1) s += __shfl_xor(s, off, 64);
        if (lane == 0) red[half * 4 + j][wv4] = s;
    }
    __syncthreads();
    if (t < PTM) {
        const float s = red[t][0] + red[t][1] + red[t][2] + red[t][3];
        qiv[t] = 1.0f / fmaxf(sqrtf(s), 1e-8f);
    }
    __syncthreads();
    #pragma unroll
    for (int j = 0; j < 4; ++j)
        qb[(size_t)(m0 + half * 4 + j) * D_E + e] =
            bf16bits(q[j] * qiv[half * 4 + j]);
}

// ---------------------------------------------------------------------------
// Kernel 2 (v10): r8's proven compute core, NEW sync structure (T4 counted
// vmcnt + raw s_barrier — never vmcnt(0) in the loop):
//   per tile: vmcnt(4) [this tile's stage done; prev stores stay in flight]
//             -> s_barrier -> issue next stage -> ds_read+MFMA (setprio)
//             -> stores (drain during the NEXT tile, never waited on).
// One barrier, one counted waitcnt per tile. 8 waves, 128 KB LDS, grid 252.
// ---------------------------------------------------------------------------
#define BM 128
#define BN 64
#define TPB 25
#define NGRPN 63                        // 63*25*64 = 100800 >= 100000
#define SIM_GRID (NGRPN * (M_TOT / BM))   // 252

__global__ __launch_bounds__(512, 2) void sim_kernel(
    const unsigned short* __restrict__ eb, const unsigned short* __restrict__ qb,
    float* __restrict__ out)
{
    __shared__ unsigned short qs[BM * D_E];       // 64 KB
    __shared__ unsigned short es[2][BN * D_E];    // 2 x 32 KB

    const int t    = threadIdx.x;
    const int lane = t & 63;
    const int wid  = t >> 6;        // 0..7
    const int l15  = lane & 15;
    const int lk   = lane >> 4;     // 0..3
    const int wm   = (wid >> 1) * 32;   // 0,32,64,96
    const int wn   = (wid & 1) * 32;    // 0,32

    int vbid;
    {
        const int q = SIM_GRID >> 3, r = SIM_GRID & 7;   // 31, 4
        const int xcd = blockIdx.x & 7, rk = blockIdx.x >> 3;
        vbid = (xcd < r ? xcd * (q + 1) : r * (q + 1) + (xcd - r) * q) + rk;
    }
    const int mg    = vbid & 3;
    const int ngrp  = vbid >> 2;            // 0..62
    const int m0    = mg * BM;
    const int nbase = ngrp * (TPB * BN);    // ngrp * 1600

    // ---- prologue: stage q tile (8 chunks/thr) + entity tile 0 (4) ----
    #pragma unroll
    for (int i = 0; i < 8; ++i) {
        const int c   = i * 512 + t;
        const int row = c >> 5;             // 0..127
        const int c16 = c & 31;
        const unsigned short* src =
            qb + (size_t)(m0 + row) * D_E + ((c16 ^ (row & 7)) << 3);
        gload_lds16(src, (void*)&qs[(size_t)c << 3]);
    }
    #pragma unroll
    for (int i = 0; i < 4; ++i) {
        const int c   = i * 512 + t;
        const int row = c >> 5;             // 0..63
        const int c16 = c & 31;
        int rg = nbase + row; if (rg >= E_TOT) rg = E_TOT - 1;
        const unsigned short* src =
            eb + (size_t)rg * D_E + ((c16 ^ (row & 7)) << 3);
        gload_lds16(src, (void*)&es[0][(size_t)c << 3]);
    }

    const char* qsb = reinterpret_cast<const char*>(qs);

    for (int tt = 0; tt < TPB; ++tt) {
        const int n0 = nbase + tt * BN;
        if (n0 >= E_TOT) break;             // block-uniform
        const int cur = tt & 1;

        // wait: this tile's stage (issued last iter / prologue) retired.
        // vmcnt(4) leaves the previous tile's 4 stores in flight (T4).
        if (tt == 0) {
            asm volatile("s_waitcnt vmcnt(0)" ::: "memory");
        } else {
            asm volatile("s_waitcnt vmcnt(4)" ::: "memory");
        }
        __builtin_amdgcn_s_barrier();       // all waves' stage portions done
        __builtin_amdgcn_sched_barrier(0);  // pin: nothing hoists above

        // issue next tile's stage into the other buffer (after barrier:
        // no wave can still be reading buf^1 — its reads finished before
        // the PREVIOUS barrier).
        const int nn0 = n0 + BN;
        if (tt + 1 < TPB && nn0 < E_TOT) {
            #pragma unroll
            for (int i = 0; i < 4; ++i) {
                const int c   = i * 512 + t;
                const int row = c >> 5;
                const int c16 = c & 31;
                int rg = nn0 + row; if (rg >= E_TOT) rg = E_TOT - 1;
                const unsigned short* src =
                    eb + (size_t)rg * D_E + ((c16 ^ (row & 7)) << 3);
                gload_lds16(src, (void*)&es[cur ^ 1][(size_t)c << 3]);
            }
        }

        const char* esb = reinterpret_cast<const char*>(&es[cur][0]);

        f32x4 acc[2][2];
        #pragma unroll
        for (int mf = 0; mf < 2; ++mf)
            #pragma unroll
            for (int nf = 0; nf < 2; ++nf)
                acc[mf][nf] = (f32x4){0.f, 0.f, 0.f, 0.f};

        __builtin_amdgcn_s_setprio(1);
        #pragma unroll
        for (int ks = 0; ks < 8; ++ks) {
            const int kb = ks * 64 + lk * 16;
            bf16x8 ef[2];
            #pragma unroll
            for (int nf = 0; nf < 2; ++nf) {
                const int row = wn + nf * 16 + l15;
                const int cb  = kb ^ ((row & 7) << 4);
                ef[nf] = *reinterpret_cast<const bf16x8*>(esb + row * 512 + cb);
            }
            #pragma unroll
            for (int mf = 0; mf < 2; ++mf) {
                const int rq  = wm + mf * 16 + l15;
                const int cbq = kb ^ ((rq & 7) << 4);
                const bf16x8 qf =
                    *reinterpret_cast<const bf16x8*>(qsb + rq * 512 + cbq);
                acc[mf][0] = __builtin_amdgcn_mfma_f32_16x16x32_bf16(
                    ef[0], qf, acc[mf][0], 0, 0, 0);
                acc[mf][1] = __builtin_amdgcn_mfma_f32_16x16x32_bf16(
                    ef[1], qf, acc[mf][1], 0, 0, 0);
            }
        }
        __builtin_amdgcn_s_setprio(0);

        // stores: issued now, drained during the NEXT tile's compute —
        // never inside a waitcnt(0) (the r8 bottleneck).
        #pragma unroll
        for (int mf = 0; mf < 2; ++mf) {
            const int m = m0 + wm + mf * 16 + l15;
            #pragma unroll
            for (int nf = 0; nf < 2; ++nf) {
                const int n = n0 + wn + nf * 16 + lk * 4;
                if (n < E_TOT)
                    *reinterpret_cast<f32x4*>(&out[(size_t)m * E_TOT + n]) =
                        acc[mf][nf];
            }
        }
    }
}

// ---------------------------------------------------------------------------
extern "C" void kernel_launch(void* const* d_in, const int* in_sizes, int n_in,
                              void* d_out, int out_size, void* d_ws, size_t ws_size,
                              hipStream_t stream) {
    const float* x  = (const float*)d_in[0];   // [4,128,768]
    const float* W  = (const float*)d_in[1];   // [256,768]
    const float* b  = (const float*)d_in[2];   // [256]
    const float* en = (const float*)d_in[3];   // [100000,256]
    float* out = (float*)d_out;                // [512,100000]

    unsigned short* qb = (unsigned short*)d_ws;                 // 256 KB
    unsigned short* eb = (unsigned short*)((char*)d_ws + (size_t)M_TOT * D_E * 2);

    fused_pp<<<PP_GRID, 512, 0, stream>>>(x, W, b, en, qb, eb); // 1627 blocks
    sim_kernel<<<SIM_GRID, 512, 0, stream>>>(eb, qb, out);      // 252 blocks
}